// Round 5
// baseline (1296.427 us; speedup 1.0000x reference)
//
#include <hip/hip_runtime.h>
#include <hip/hip_bf16.h>
#include <math.h>

// ---------------- problem constants ----------------
#define T_TOK 16384
#define HID   1024
#define FFN   2816
#define NE    8
#define CAP   5120               // ceil(16384*1.25*2/8)
#define NASSIGN (T_TOK*2)        // 32768
#define NWAVE   (NASSIGN/64)     // 512

#define WB_E ((size_t)HID*FFN)   // elements per expert weight matrix
#define GB_E ((size_t)CAP*FFN)   // elements per expert G

// ---------------- fixed small-buffer workspace layout (bytes) ----------------
#define OFF_TOPIDX 0ull
#define OFF_TOPW   (OFF_TOPIDX + (size_t)T_TOK*8)
#define OFF_WCNT   (OFF_TOPW   + (size_t)T_TOK*8)
#define OFF_WOFF   (OFF_WCNT   + (size_t)NWAVE*NE*4)
#define OFF_USED   (OFF_WOFF   + (size_t)NWAVE*NE*4)
#define OFF_AE     (OFF_USED   + 256)
#define OFF_AR     (OFF_AE     + (size_t)NASSIGN*4)
#define OFF_TOS    (OFF_AR     + (size_t)NASSIGN*4)
#define OFF_WSL    (OFF_TOS    + (size_t)NE*CAP*4)
#define OFF_XB     (OFF_WSL    + (size_t)NE*CAP*4)
#define OFF_WT     (OFF_XB     + (size_t)T_TOK*HID*2)      // weight area starts here

typedef __bf16 bf16x8 __attribute__((ext_vector_type(8)));
typedef float  f32x4  __attribute__((ext_vector_type(4)));

static __device__ __forceinline__ unsigned short f2bf(float f) {
    unsigned int u = __float_as_uint(f);
    unsigned int r = u + 0x7fffu + ((u >> 16) & 1u);   // round-to-nearest-even
    return (unsigned short)(r >> 16);
}

// async global->LDS, 16 bytes per lane; LDS dest = wave-uniform base + lane*16
static __device__ __forceinline__ void gload16(const void* g, void* l) {
    __builtin_amdgcn_global_load_lds(
        (const __attribute__((address_space(1))) unsigned int*)g,
        (__attribute__((address_space(3))) unsigned int*)l, 16, 0, 0);
}

// T1 XCD swizzle over a 1-D grid (bijective: total % 8 == 0 always here)
static __device__ __forceinline__ int xcd_swz1d(int total) {
    int lid = blockIdx.x;
    return (lid & 7) * (total >> 3) + (lid >> 3);
}

// ---------------- K0: fp32 [R][C] -> bf16 [C][R], expert z ----------------
__global__ __launch_bounds__(256) void k_transpose_cvt(
    const float* __restrict__ in, unsigned short* __restrict__ outb, int R, int C)
{
    __shared__ float tile[32][33];
    const float* inp = in + (size_t)blockIdx.z * R * C;
    unsigned short* outp = outb + (size_t)blockIdx.z * R * C;
    const int r0 = blockIdx.y * 32, c0 = blockIdx.x * 32;
    const int tr = threadIdx.x >> 5, tc = threadIdx.x & 31;   // tr 0..7
#pragma unroll
    for (int p = 0; p < 4; ++p)
        tile[tr + 8*p][tc] = inp[(size_t)(r0 + tr + 8*p) * C + c0 + tc];
    __syncthreads();
#pragma unroll
    for (int p = 0; p < 4; ++p)
        outp[(size_t)(c0 + tr + 8*p) * R + r0 + tc] = f2bf(tile[tc][tr + 8*p]);
}

// ---------------- K1: gating (fp32 logits + top-2 + softmax) + x->bf16 ----------------
__global__ __launch_bounds__(256) void k_gate(
    const float* __restrict__ x, const float* __restrict__ Wg,
    int2* __restrict__ top_idx, float2* __restrict__ top_w,
    unsigned short* __restrict__ xb)
{
    __shared__ float wgT[NE * HID];          // transposed: [e][h]
    const int tid = threadIdx.x;
    for (int idx = tid; idx < NE * HID; idx += 256) {
        int h = idx >> 3, e = idx & 7;
        wgT[e * HID + h] = Wg[idx];
    }
    __syncthreads();
    const int wave = tid >> 6, lane = tid & 63;
    const int t = blockIdx.x * 4 + wave;     // one wave per token
    float a[NE];
#pragma unroll
    for (int e = 0; e < NE; ++e) a[e] = 0.f;
    const float* xr = x + (size_t)t * HID;
    unsigned short* xbr = xb + (size_t)t * HID;
    for (int j = 0; j < HID / 64; ++j) {
        float xv = xr[j * 64 + lane];
        xbr[j * 64 + lane] = f2bf(xv);       // fused x->bf16 (x streamed once)
#pragma unroll
        for (int e = 0; e < NE; ++e)
            a[e] = fmaf(xv, wgT[e * HID + j * 64 + lane], a[e]);
    }
#pragma unroll
    for (int e = 0; e < NE; ++e) {
#pragma unroll
        for (int off = 32; off > 0; off >>= 1)
            a[e] += __shfl_xor(a[e], off, 64);
    }
    if (lane == 0) {
        float v0 = -1e30f, v1 = -1e30f; int i0 = 0, i1 = 0;
#pragma unroll
        for (int e = 0; e < NE; ++e) {
            float v = a[e];
            if (v > v0)      { v1 = v0; i1 = i0; v0 = v; i0 = e; }  // ties -> lowest idx
            else if (v > v1) { v1 = v;  i1 = e; }
        }
        float e1 = expf(v1 - v0);            // softmax over [v0,v1], v0 = max
        float s  = 1.f + e1;
        top_idx[t] = make_int2(i0, i1);
        top_w[t]   = make_float2(1.f / s, e1 / s);
    }
}

// ---------------- K2: per-wave expert counts + in-wave ranks ----------------
__global__ __launch_bounds__(256) void k_count(
    const int2* __restrict__ top_idx, int* __restrict__ wcnt,
    int* __restrict__ ae, int* __restrict__ ar)
{
    const int i = blockIdx.x * 256 + threadIdx.x;     // assignment id = t*2 + k
    const int2 ti = top_idx[i >> 1];
    const int e = (i & 1) ? ti.y : ti.x;
    const int lane = threadIdx.x & 63;
    const int wid = i >> 6;
    const unsigned long long lt = (1ull << lane) - 1ull;
    int rank = 0;
#pragma unroll
    for (int ex = 0; ex < NE; ++ex) {
        unsigned long long m = __ballot(e == ex);
        if (e == ex)    rank = __popcll(m & lt);
        if (lane == ex) wcnt[wid * NE + ex] = __popcll(m);
    }
    ae[i] = e; ar[i] = rank;
}

// ---------------- K3: exclusive scan of wave counts (1 block) ----------------
__global__ __launch_bounds__(NWAVE) void k_scan(
    const int* __restrict__ wcnt, int* __restrict__ woff, int* __restrict__ used)
{
    __shared__ int sb[NWAVE];
    const int tid = threadIdx.x;
    for (int ex = 0; ex < NE; ++ex) {
        int v = wcnt[tid * NE + ex];
        sb[tid] = v;
        __syncthreads();
        for (int off = 1; off < NWAVE; off <<= 1) {
            int p = (tid >= off) ? sb[tid - off] : 0;
            __syncthreads();
            sb[tid] += p;
            __syncthreads();
        }
        woff[tid * NE + ex] = sb[tid] - v;
        if (tid == NWAVE - 1) used[ex] = min(sb[tid], CAP);
        __syncthreads();
    }
}

// ---------------- K4: emit token_of_slot + weight_of_slot ----------------
__global__ __launch_bounds__(256) void k_emit(
    const int* __restrict__ ae, const int* __restrict__ ar,
    const int* __restrict__ woff, const float2* __restrict__ top_w,
    int* __restrict__ tos, float* __restrict__ wsl)
{
    const int i = blockIdx.x * 256 + threadIdx.x;
    const int e = ae[i];
    const int pos = woff[(i >> 6) * NE + e] + ar[i];
    if (pos < CAP) {
        const int slot = e * CAP + pos;
        tos[slot] = i >> 1;
        const float2 w = top_w[i >> 1];
        wsl[slot] = (i & 1) ? w.y : w.x;
    }
}

// ---------------- K5: fused GEMM1+GEMM3 + SwiGLU (bf16 MFMA) ----------------
// 128x128 tile, BK=32, 4 waves x 64x64 (4x4 frags of 16x16x32), m97 structure.
// e0: first expert of this pass; we0: expert base of weight buffers; ec: experts/pass.
__global__ __launch_bounds__(256, 2) void k_gemm13(
    const unsigned short* __restrict__ xb,
    const unsigned short* __restrict__ W1t,   // [(e-we0)][F][H] bf16
    const unsigned short* __restrict__ W3t,
    const int* __restrict__ tos, const int* __restrict__ used_arr,
    unsigned short* __restrict__ G,           // [(e-e0)][CAP][F] bf16
    int e0, int we0, int ec)
{
    __shared__ __align__(16) unsigned short As[128 * 32];   // [row][k]
    __shared__ __align__(16) unsigned short B1s[128 * 32];  // [n][k]
    __shared__ __align__(16) unsigned short B3s[128 * 32];
    __shared__ int toks[128];

    const int logical = xcd_swz1d(880 * ec);   // 880 = 40*22 blocks per expert
    const int bx = logical % 40;
    const int by = (logical / 40) % 22;
    const int e  = e0 + logical / 880;

    const int used = used_arr[e];
    const int row0 = bx * 128;
    if (row0 >= used) return;
    const int col0 = by * 128;
    const int tid = threadIdx.x;

    if (tid < 128) { int r = row0 + tid; toks[tid] = (r < used) ? tos[e * CAP + r] : 0; }
    __syncthreads();

    const int qr = tid >> 2, qk = (tid & 3) * 8;            // per-lane gather mapping
    const unsigned short* srcA0 = xb + (size_t)toks[qr] * HID + qk;
    const unsigned short* srcA1 = xb + (size_t)toks[64 + qr] * HID + qk;
    const unsigned short* w1e = W1t + (size_t)(e - we0) * WB_E;
    const unsigned short* w3e = W3t + (size_t)(e - we0) * WB_E;
    const unsigned short* srcB1_0 = w1e + (size_t)(col0 + qr) * HID + qk;
    const unsigned short* srcB1_1 = w1e + (size_t)(col0 + 64 + qr) * HID + qk;
    const unsigned short* srcB3_0 = w3e + (size_t)(col0 + qr) * HID + qk;
    const unsigned short* srcB3_1 = w3e + (size_t)(col0 + 64 + qr) * HID + qk;

    const int wv = tid >> 6, lane = tid & 63;
    unsigned short* dA0 = As + wv * 512;          // wave-uniform LDS bases
    unsigned short* dA1 = As + 2048 + wv * 512;
    unsigned short* dB1_0 = B1s + wv * 512;
    unsigned short* dB1_1 = B1s + 2048 + wv * 512;
    unsigned short* dB3_0 = B3s + wv * 512;
    unsigned short* dB3_1 = B3s + 2048 + wv * 512;

    f32x4 acc1[4][4], acc3[4][4];
#pragma unroll
    for (int m = 0; m < 4; ++m)
#pragma unroll
        for (int n = 0; n < 4; ++n) {
            acc1[m][n] = {0.f, 0.f, 0.f, 0.f};
            acc3[m][n] = {0.f, 0.f, 0.f, 0.f};
        }

    const int mb = (wv >> 1) * 64, nb = (wv & 1) * 64;
    const int fr = lane & 15, kh = (lane >> 4) * 8;

    for (int k0 = 0; k0 < HID; k0 += 32) {
        gload16(srcA0, dA0);     gload16(srcA1, dA1);
        gload16(srcB1_0, dB1_0); gload16(srcB1_1, dB1_1);
        gload16(srcB3_0, dB3_0); gload16(srcB3_1, dB3_1);
        srcA0 += 32; srcA1 += 32;
        srcB1_0 += 32; srcB1_1 += 32; srcB3_0 += 32; srcB3_1 += 32;
        __syncthreads();          // drains vmcnt (loads landed) before LDS reads
        bf16x8 a[4], b1[4], b3[4];
#pragma unroll
        for (int m = 0; m < 4; ++m)
            a[m] = *(const bf16x8*)&As[(mb + m * 16 + fr) * 32 + kh];
#pragma unroll
        for (int n = 0; n < 4; ++n) {
            b1[n] = *(const bf16x8*)&B1s[(nb + n * 16 + fr) * 32 + kh];
            b3[n] = *(const bf16x8*)&B3s[(nb + n * 16 + fr) * 32 + kh];
        }
#pragma unroll
        for (int m = 0; m < 4; ++m)
#pragma unroll
            for (int n = 0; n < 4; ++n) {
                acc1[m][n] = __builtin_amdgcn_mfma_f32_16x16x32_bf16(a[m], b1[n], acc1[m][n], 0, 0, 0);
                acc3[m][n] = __builtin_amdgcn_mfma_f32_16x16x32_bf16(a[m], b3[n], acc3[m][n], 0, 0, 0);
            }
        __syncthreads();          // protect LDS before next stage
    }

    unsigned short* Ge = G + (size_t)(e - e0) * GB_E;
    const int cr = (lane >> 4) * 4, cc = lane & 15;   // C/D: col=lane&15, row=(lane>>4)*4+j
#pragma unroll
    for (int m = 0; m < 4; ++m)
#pragma unroll
        for (int j = 0; j < 4; ++j) {
            const int r = row0 + mb + m * 16 + cr + j;
            if (r < used) {
#pragma unroll
                for (int n = 0; n < 4; ++n) {
                    float h1 = acc1[m][n][j], h3 = acc3[m][n][j];
                    float g = h1 / (1.f + __expf(-h1)) * h3;   // silu(h1)*h3
                    Ge[(size_t)r * FFN + col0 + nb + n * 16 + cc] = f2bf(g);
                }
            }
        }
}

// ---------------- K6: GEMM2 (G @ W2) + fused weighted atomic combine ----------------
__global__ __launch_bounds__(256, 2) void k_gemm2(
    const unsigned short* __restrict__ G,
    const unsigned short* __restrict__ W2t,   // [(e-we0)][H][F] bf16
    const int* __restrict__ tos, const float* __restrict__ wsl,
    const int* __restrict__ used_arr, float* __restrict__ out,
    int e0, int we0, int ec)
{
    __shared__ __align__(16) unsigned short As[128 * 32];
    __shared__ __align__(16) unsigned short Bs[128 * 32];

    const int logical = xcd_swz1d(320 * ec);   // 320 = 40*8 blocks per expert
    const int bx = logical % 40;
    const int by = (logical / 40) % 8;
    const int e  = e0 + logical / 320;

    const int used = used_arr[e];
    const int row0 = bx * 128;
    if (row0 >= used) return;
    const int col0 = by * 128;
    const int tid = threadIdx.x;

    const int qr = tid >> 2, qk = (tid & 3) * 8;
    const unsigned short* Ge = G + (size_t)(e - e0) * GB_E;
    const unsigned short* srcA0 = Ge + (size_t)(row0 + qr) * FFN + qk;
    const unsigned short* srcA1 = Ge + (size_t)(row0 + 64 + qr) * FFN + qk;
    const unsigned short* w2e = W2t + (size_t)(e - we0) * WB_E;
    const unsigned short* srcB0 = w2e + (size_t)(col0 + qr) * FFN + qk;
    const unsigned short* srcB1 = w2e + (size_t)(col0 + 64 + qr) * FFN + qk;

    const int wv = tid >> 6, lane = tid & 63;
    unsigned short* dA0 = As + wv * 512;
    unsigned short* dA1 = As + 2048 + wv * 512;
    unsigned short* dB0 = Bs + wv * 512;
    unsigned short* dB1 = Bs + 2048 + wv * 512;

    f32x4 acc[4][4];
#pragma unroll
    for (int m = 0; m < 4; ++m)
#pragma unroll
        for (int n = 0; n < 4; ++n) acc[m][n] = {0.f, 0.f, 0.f, 0.f};

    const int mb = (wv >> 1) * 64, nb = (wv & 1) * 64;
    const int fr = lane & 15, kh = (lane >> 4) * 8;

    for (int k0 = 0; k0 < FFN; k0 += 32) {
        gload16(srcA0, dA0); gload16(srcA1, dA1);
        gload16(srcB0, dB0); gload16(srcB1, dB1);
        srcA0 += 32; srcA1 += 32; srcB0 += 32; srcB1 += 32;
        __syncthreads();
        bf16x8 a[4], b[4];
#pragma unroll
        for (int m = 0; m < 4; ++m)
            a[m] = *(const bf16x8*)&As[(mb + m * 16 + fr) * 32 + kh];
#pragma unroll
        for (int n = 0; n < 4; ++n)
            b[n] = *(const bf16x8*)&Bs[(nb + n * 16 + fr) * 32 + kh];
#pragma unroll
        for (int m = 0; m < 4; ++m)
#pragma unroll
            for (int n = 0; n < 4; ++n)
                acc[m][n] = __builtin_amdgcn_mfma_f32_16x16x32_bf16(a[m], b[n], acc[m][n], 0, 0, 0);
        __syncthreads();
    }

    const int cr = (lane >> 4) * 4, cc = lane & 15;
#pragma unroll
    for (int m = 0; m < 4; ++m)
#pragma unroll
        for (int j = 0; j < 4; ++j) {
            const int r = row0 + mb + m * 16 + cr + j;
            if (r < used) {
                const int slot = e * CAP + r;
                const int t = tos[slot];
                const float w = wsl[slot];
                float* orow = out + (size_t)t * HID + col0 + nb + cc;
#pragma unroll
                for (int n = 0; n < 4; ++n)
                    atomicAdd(orow + n * 16, w * acc[m][n][j]);
            }
        }
}

// ---------------- launcher ----------------
extern "C" void kernel_launch(void* const* d_in, const int* in_sizes, int n_in,
                              void* d_out, int out_size, void* d_ws, size_t ws_size,
                              hipStream_t stream)
{
    const float* x  = (const float*)d_in[0];
    const float* Wg = (const float*)d_in[1];
    const float* W1 = (const float*)d_in[2];
    const float* W3 = (const float*)d_in[3];
    const float* W2 = (const float*)d_in[4];
    float* out = (float*)d_out;
    char* ws = (char*)d_ws;

    const size_t wmat = WB_E * 2;             // 5.77 MB per expert per matrix
    const size_t gmat = GB_E * 2;             // 28.8 MB per expert
    const size_t base = OFF_WT;

    // tier selection (ws_size is constant across calls -> capture-safe)
    int EC = 0; bool chunkW = false;
    const size_t fullW_end = base + 3 * (size_t)NE * wmat;
    if      (ws_size >= fullW_end + 8 * gmat) { EC = 8; }
    else if (ws_size >= fullW_end + 4 * gmat) { EC = 4; }
    else if (ws_size >= fullW_end + 2 * gmat) { EC = 2; }
    else if (ws_size >= fullW_end + 1 * gmat) { EC = 1; }
    else if (ws_size >= base + 3 * wmat + gmat) { EC = 1; chunkW = true; }
    else {
        hipMemsetAsync(d_out, 0xFF, 2048, stream);   // ws too small: NaN signature
        return;
    }

    int2*   top_idx = (int2*)(ws + OFF_TOPIDX);
    float2* top_w   = (float2*)(ws + OFF_TOPW);
    int*   wcnt = (int*)(ws + OFF_WCNT);
    int*   woff = (int*)(ws + OFF_WOFF);
    int*   used = (int*)(ws + OFF_USED);
    int*   ae   = (int*)(ws + OFF_AE);
    int*   ar   = (int*)(ws + OFF_AR);
    int*   tos  = (int*)(ws + OFF_TOS);
    float* wsl  = (float*)(ws + OFF_WSL);
    unsigned short* xb  = (unsigned short*)(ws + OFF_XB);
    const int nw = chunkW ? 1 : NE;           // experts resident in weight buffers
    unsigned short* W1t = (unsigned short*)(ws + base);
    unsigned short* W3t = W1t + (size_t)nw * WB_E;
    unsigned short* W2t = W3t + (size_t)nw * WB_E;
    unsigned short* G   = W2t + (size_t)nw * WB_E;

    hipMemsetAsync(out, 0, (size_t)T_TOK * HID * 4, stream);

    // gating + dispatch (weight-independent)
    k_gate<<<dim3(T_TOK / 4), dim3(256), 0, stream>>>(x, Wg, top_idx, top_w, xb);
    k_count<<<dim3(NASSIGN / 256), dim3(256), 0, stream>>>(top_idx, wcnt, ae, ar);
    k_scan<<<dim3(1), dim3(NWAVE), 0, stream>>>(wcnt, woff, used);
    k_emit<<<dim3(NASSIGN / 256), dim3(256), 0, stream>>>(ae, ar, woff, top_w, tos, wsl);

    if (!chunkW) {
        k_transpose_cvt<<<dim3(FFN / 32, HID / 32, NE), dim3(256), 0, stream>>>(W1, W1t, HID, FFN);
        k_transpose_cvt<<<dim3(FFN / 32, HID / 32, NE), dim3(256), 0, stream>>>(W3, W3t, HID, FFN);
        k_transpose_cvt<<<dim3(HID / 32, FFN / 32, NE), dim3(256), 0, stream>>>(W2, W2t, FFN, HID);
    }

    for (int e0 = 0; e0 < NE; e0 += EC) {
        const int we0 = chunkW ? e0 : 0;
        if (chunkW) {
            const size_t off = (size_t)e0 * WB_E;
            k_transpose_cvt<<<dim3(FFN / 32, HID / 32, 1), dim3(256), 0, stream>>>(W1 + off, W1t, HID, FFN);
            k_transpose_cvt<<<dim3(FFN / 32, HID / 32, 1), dim3(256), 0, stream>>>(W3 + off, W3t, HID, FFN);
            k_transpose_cvt<<<dim3(HID / 32, FFN / 32, 1), dim3(256), 0, stream>>>(W2 + off, W2t, FFN, HID);
        }
        k_gemm13<<<dim3(880 * EC), dim3(256), 0, stream>>>(xb, W1t, W3t, tos, used, G, e0, we0, EC);
        k_gemm2<<<dim3(320 * EC), dim3(256), 0, stream>>>(G, W2t, tos, wsl, used, out, e0, we0, EC);
    }
}